// Round 1
// baseline (131.333 us; speedup 1.0000x reference)
//
#include <hip/hip_runtime.h>

// NTN: out[n,k] = relu( cos(x1 @ W1[k], x2 @ W2[k]) + [x1,x2]·V[k] + b[k] )
// N=32768, D=128, K=16.  Strategy:
//  - prep kernel: W1,W2 -> bf16 in MFMA A-operand (W^T) fragment lane order in ws;
//    V -> bf16 A-operand fragment order.
//  - main kernel: 256 blocks x 256 thr (4 waves, 32 rows/wave). X row fragments
//    (B-operand, k-invariant) converted to bf16 and held in registers.
//    k-loop streams W[k] per-side 32KB chunks via global_load_lds into a 2-slot
//    LDS ring (64KB total). GEMM is computed transposed (M=e, N=rows) so the
//    e-reduction is per-lane FMAs + shfl_xor(16)+shfl_xor(32).
//  - part2 + b computed once via MFMA (A=V fragments, B=X fragments) and stored
//    to d_out; per-k epilogue does wave-private RMW: relu(part1 + stored).

typedef __attribute__((ext_vector_type(8))) __bf16 bf16x8;
typedef __attribute__((ext_vector_type(8))) unsigned short us8;
typedef __attribute__((ext_vector_type(4))) float f32x4;

static __device__ __forceinline__ unsigned short f2bf(float f) {
  unsigned u = __float_as_uint(f);
  u += 0x7FFFu + ((u >> 16) & 1u);   // round-to-nearest-even
  return (unsigned short)(u >> 16);
}

static __device__ __forceinline__ bf16x8 as_bf(us8 u) {
  bf16x8 r;
  __builtin_memcpy(&r, &u, sizeof(r));
  return r;
}

// ---------------- prep: swizzle W and V into bf16 fragment order ----------------
// wsW layout: chunk cc = k*2+side (32KB each, 2048 units of 16B).
//   unit (et*4+s)*64+lane holds frag[j] = W[k][d = s*32 + (lane>>4)*8 + j][e = et*16 + (lane&15)]
// wsV layout: unit cs*64+lane holds frag[j] = V[lane&15][c = cs*32 + (lane>>4)*8 + j]
__global__ void ntn_prep(const float* __restrict__ W1, const float* __restrict__ W2,
                         const float* __restrict__ V,
                         unsigned short* __restrict__ wsW, unsigned short* __restrict__ wsV) {
  int t = blockIdx.x * 256 + threadIdx.x;
  if (t < 65536) {
    int u = t & 2047;
    int lane = u & 63, s = (u >> 6) & 3, et = (u >> 8) & 7;
    int cc = t >> 11, side = cc & 1, k = cc >> 1;
    int q = lane >> 4, l15 = lane & 15;
    const float* W = side ? W2 : W1;
    const float* src = W + k * 16384 + (s * 32 + q * 8) * 128 + (et * 16 + l15);
    us8 r;
#pragma unroll
    for (int j = 0; j < 8; ++j) r[j] = f2bf(src[j * 128]);
    *(us8*)(wsW + (size_t)t * 8) = r;
  } else if (t < 66048) {
    int u = t - 65536;
    int lane = u & 63, cs = u >> 6;
    int q = lane >> 4, l15 = lane & 15;
    const float* src = V + l15 * 256 + cs * 32 + q * 8;
    us8 r;
#pragma unroll
    for (int j = 0; j < 8; ++j) r[j] = f2bf(src[j]);
    *(us8*)(wsV + (size_t)u * 8) = r;
  }
}

// ---------------- main ----------------
__global__ __launch_bounds__(256, 1) void ntn_main(
    const float* __restrict__ x1, const float* __restrict__ x2,
    const float* __restrict__ b,
    const unsigned short* __restrict__ wsW, const unsigned short* __restrict__ wsV,
    float* __restrict__ out) {
  __shared__ uint4 ldsW[2][2048];   // two 32KB chunk slots = 64KB

  const int tid = threadIdx.x;
  const int lane = tid & 63, wave = tid >> 6;
  const int q = lane >> 4, l15 = lane & 15;
  const int rowbase = blockIdx.x * 128 + wave * 32;

  const f32x4 zero4 = {0.f, 0.f, 0.f, 0.f};

  // ---- X fragments (B-operand), bf16, k-invariant, kept in registers ----
  // frag[j] = X[row = tile*16 + (lane&15)][d = s*32 + (lane>>4)*8 + j]
  bf16x8 xb[2][2][4];
#pragma unroll
  for (int side = 0; side < 2; ++side) {
    const float* xp0 = side ? x2 : x1;
#pragma unroll
    for (int nt = 0; nt < 2; ++nt) {
#pragma unroll
      for (int s = 0; s < 4; ++s) {
        const float* p = xp0 + (size_t)(rowbase + nt * 16 + l15) * 128 + s * 32 + q * 8;
        float4 v0 = *(const float4*)p;
        float4 v1 = *(const float4*)(p + 4);
        us8 uu;
        uu[0] = f2bf(v0.x); uu[1] = f2bf(v0.y); uu[2] = f2bf(v0.z); uu[3] = f2bf(v0.w);
        uu[4] = f2bf(v1.x); uu[5] = f2bf(v1.y); uu[6] = f2bf(v1.z); uu[7] = f2bf(v1.w);
        xb[side][nt][s] = as_bf(uu);
      }
    }
  }

  // async stage of W chunk into an LDS slot: 32KB, 8 glds x (64 lanes x 16B) per wave
  auto stage = [&](int cc, int slot) {
    const unsigned short* src = wsW + (size_t)cc * 16384 + (size_t)(wave * 512 + lane) * 8;
    uint4* dst = &ldsW[slot][wave * 512];
#pragma unroll
    for (int i = 0; i < 8; ++i)
      __builtin_amdgcn_global_load_lds(
          (__attribute__((address_space(1))) void*)(void*)(src + i * 512),
          (__attribute__((address_space(3))) void*)(dst + i * 64), 16, 0, 0);
  };

  stage(0, 0);   // chunk 0 = (k=0, W1)

  // ---- part2 + b via MFMA (A = V frags: M=k-index; B = X frags), store to out ----
  {
    bf16x8 vf[8];
#pragma unroll
    for (int cs = 0; cs < 8; ++cs)
      vf[cs] = as_bf(*(const us8*)(wsV + (size_t)(cs * 64 + lane) * 8));
    float4 bv = *(const float4*)(b + q * 4);
#pragma unroll
    for (int nt = 0; nt < 2; ++nt) {
      f32x4 accP = zero4;
#pragma unroll
      for (int cs = 0; cs < 8; ++cs)
        accP = __builtin_amdgcn_mfma_f32_16x16x32_bf16(vf[cs], xb[cs >> 2][nt][cs & 3], accP, 0, 0, 0);
      accP.x += bv.x; accP.y += bv.y; accP.z += bv.z; accP.w += bv.w;
      int row = rowbase + nt * 16 + l15;
      *(f32x4*)(out + (size_t)row * 16 + q * 4) = accP;   // k = q*4 + reg, contiguous
    }
  }

  // ---- k loop: side0 chunk -> acc1 (T1 tiles); side1 chunk -> T2 + fused reduction ----
  f32x4 acc1[8][2];
#pragma unroll 1
  for (int k = 0; k < 16; ++k) {
    __syncthreads();               // chunk 2k arrived in slot0; slot1 free
    stage(2 * k + 1, 1);
#pragma unroll
    for (int et = 0; et < 8; ++et) {
      bf16x8 wa[4];
#pragma unroll
      for (int s = 0; s < 4; ++s)
        wa[s] = as_bf(*(const us8*)&ldsW[0][(et * 4 + s) * 64 + lane]);
#pragma unroll
      for (int nt = 0; nt < 2; ++nt) {
        f32x4 a = zero4;
#pragma unroll
        for (int s = 0; s < 4; ++s)
          a = __builtin_amdgcn_mfma_f32_16x16x32_bf16(wa[s], xb[0][nt][s], a, 0, 0, 0);
        acc1[et][nt] = a;
      }
    }
    __syncthreads();               // chunk 2k+1 arrived in slot1; slot0 free
    if (k < 15) stage(2 * k + 2, 0);

    float nm[2] = {0.f, 0.f}, q1[2] = {0.f, 0.f}, q2[2] = {0.f, 0.f};
#pragma unroll
    for (int et = 0; et < 8; ++et) {
      bf16x8 wb[4];
#pragma unroll
      for (int s = 0; s < 4; ++s)
        wb[s] = as_bf(*(const us8*)&ldsW[1][(et * 4 + s) * 64 + lane]);
#pragma unroll
      for (int nt = 0; nt < 2; ++nt) {
        f32x4 a2 = zero4;
#pragma unroll
        for (int s = 0; s < 4; ++s)
          a2 = __builtin_amdgcn_mfma_f32_16x16x32_bf16(wb[s], xb[1][nt][s], a2, 0, 0, 0);
        f32x4 a1 = acc1[et][nt];
        nm[nt] += a1.x * a2.x + a1.y * a2.y + a1.z * a2.z + a1.w * a2.w;
        q1[nt] += a1.x * a1.x + a1.y * a1.y + a1.z * a1.z + a1.w * a1.w;
        q2[nt] += a2.x * a2.x + a2.y * a2.y + a2.z * a2.z + a2.w * a2.w;
      }
    }
    // reduce over e: regs covered in-lane; row-groups via xor-16/32; then finalize
#pragma unroll
    for (int nt = 0; nt < 2; ++nt) {
      nm[nt] += __shfl_xor(nm[nt], 16); nm[nt] += __shfl_xor(nm[nt], 32);
      q1[nt] += __shfl_xor(q1[nt], 16); q1[nt] += __shfl_xor(q1[nt], 32);
      q2[nt] += __shfl_xor(q2[nt], 16); q2[nt] += __shfl_xor(q2[nt], 32);
      float n1 = fmaxf(sqrtf(q1[nt]), 1e-8f);
      float n2 = fmaxf(sqrtf(q2[nt]), 1e-8f);
      float p1 = nm[nt] / (n1 * n2);
      if (lane < 16) {
        float* po = out + (size_t)(rowbase + nt * 16 + lane) * 16 + k;
        *po = fmaxf(p1 + *po, 0.f);   // stored value = part2 + b (written above)
      }
    }
  }
}

extern "C" void kernel_launch(void* const* d_in, const int* in_sizes, int n_in,
                              void* d_out, int out_size, void* d_ws, size_t ws_size,
                              hipStream_t stream) {
  const float* x1 = (const float*)d_in[0];
  const float* x2 = (const float*)d_in[1];
  const float* W1 = (const float*)d_in[2];
  const float* W2 = (const float*)d_in[3];
  const float* V  = (const float*)d_in[4];
  const float* b  = (const float*)d_in[5];
  float* out = (float*)d_out;
  unsigned short* wsW = (unsigned short*)d_ws;
  unsigned short* wsV = wsW + (size_t)65536 * 8;   // 1MB offset

  ntn_prep<<<258, 256, 0, stream>>>(W1, W2, V, wsW, wsV);
  ntn_main<<<256, 256, 0, stream>>>(x1, x2, b, wsW, wsV, out);
}